// Round 1
// baseline (529.780 us; speedup 1.0000x reference)
//
#include <hip/hip_runtime.h>
#include <stdint.h>

#define N_NODES 8192
#define IN_FEAT 512
#define OUT_FEAT 256
#define LOG2E 1.4426950408889634f

typedef __bf16 b16x8 __attribute__((ext_vector_type(8)));
typedef unsigned short u16x8v __attribute__((ext_vector_type(8)));
typedef float f32x4 __attribute__((ext_vector_type(4)));

static __device__ __forceinline__ unsigned short f2bf(float f) {
    union { float f; uint32_t u; } v; v.f = f;
    uint32_t r = v.u + 0x7FFFu + ((v.u >> 16) & 1u);
    return (unsigned short)(r >> 16);
}

// K0: Wt[c][k] = bf16(W[k][c])  (256 x 512)
__global__ __launch_bounds__(256) void k0_transpose_w(const float* __restrict__ W,
                                                      unsigned short* __restrict__ Wt) {
    int tid = blockIdx.x * 256 + threadIdx.x;   // 0..131071
    int c = tid & (OUT_FEAT - 1);
    int k = tid >> 8;
    Wt[(size_t)c * IN_FEAT + k] = f2bf(W[(size_t)k * OUT_FEAT + c]);
}

// K1: h = X @ W via bf16 MFMA; writes hT bf16 [256][8192] and s1_raw/s2_raw.
// One wave per block, 16 rows x 256 cols, K=512.
__global__ __launch_bounds__(64) void k1_hgemm(const float* __restrict__ input,
                                               const unsigned short* __restrict__ Wt,
                                               const float* __restrict__ a_vec,
                                               unsigned short* __restrict__ hT,
                                               float* __restrict__ s1_raw,
                                               float* __restrict__ s2_raw) {
    int lane = threadIdx.x & 63;
    int c = lane & 15, g = lane >> 4;
    int r0 = blockIdx.x * 16;
    f32x4 acc[16];
#pragma unroll
    for (int t = 0; t < 16; ++t) acc[t] = (f32x4){0.f, 0.f, 0.f, 0.f};
    const float* arow = input + (size_t)(r0 + c) * IN_FEAT;
#pragma unroll 1
    for (int kk = 0; kk < IN_FEAT / 32; ++kk) {
        int kb = kk * 32 + 8 * g;
        float4 x0 = *(const float4*)(arow + kb);
        float4 x1 = *(const float4*)(arow + kb + 4);
        u16x8v au;
        au[0] = f2bf(x0.x); au[1] = f2bf(x0.y); au[2] = f2bf(x0.z); au[3] = f2bf(x0.w);
        au[4] = f2bf(x1.x); au[5] = f2bf(x1.y); au[6] = f2bf(x1.z); au[7] = f2bf(x1.w);
        b16x8 af = __builtin_bit_cast(b16x8, au);
#pragma unroll
        for (int t = 0; t < 16; ++t) {
            b16x8 bf = __builtin_bit_cast(b16x8,
                *(const u16x8v*)(Wt + (size_t)(16 * t + c) * IN_FEAT + kb));
            acc[t] = __builtin_amdgcn_mfma_f32_16x16x32_bf16(af, bf, acc[t], 0, 0, 0);
        }
    }
    // s1 = h@a1, s2 = h@a2 (lane holds rows 4g+r, cols 16t+c)
    float a1v[16], a2v[16];
#pragma unroll
    for (int t = 0; t < 16; ++t) {
        a1v[t] = a_vec[16 * t + c];
        a2v[t] = a_vec[OUT_FEAT + 16 * t + c];
    }
#pragma unroll
    for (int r = 0; r < 4; ++r) {
        float s1p = 0.f, s2p = 0.f;
#pragma unroll
        for (int t = 0; t < 16; ++t) { s1p += acc[t][r] * a1v[t]; s2p += acc[t][r] * a2v[t]; }
#pragma unroll
        for (int m = 1; m <= 8; m <<= 1) { s1p += __shfl_xor(s1p, m); s2p += __shfl_xor(s2p, m); }
        if (c == 0) {
            int row = r0 + 4 * g + r;
            s1_raw[row] = s1p;
            s2_raw[row] = s2p;
        }
    }
    // hT store: 4 consecutive rows per (t): 8B packed
#pragma unroll
    for (int t = 0; t < 16; ++t) {
        ushort4 pk;
        pk.x = f2bf(acc[t][0]); pk.y = f2bf(acc[t][1]);
        pk.z = f2bf(acc[t][2]); pk.w = f2bf(acc[t][3]);
        *(ushort4*)(hT + (size_t)(16 * t + c) * N_NODES + r0 + 4 * g) = pk;
    }
}

// K2: M2 = max(s2); per-row constants a_row=(s1-m)*K, m8=-0.8*m*K; s2k=s2*K
__global__ __launch_bounds__(256) void k2_prep(const float* __restrict__ s1_raw,
                                               const float* __restrict__ s2_raw,
                                               float* __restrict__ s2k,
                                               float2* __restrict__ row2) {
    __shared__ float red[256];
    int tid = threadIdx.x;
    float m = -3.0e38f;
    for (int j = tid; j < N_NODES; j += 256) m = fmaxf(m, s2_raw[j]);
    red[tid] = m;
    __syncthreads();
    for (int s = 128; s > 0; s >>= 1) {
        if (tid < s) red[tid] = fmaxf(red[tid], red[tid + s]);
        __syncthreads();
    }
    float M2 = red[0];
    for (int i = tid; i < N_NODES; i += 256) {
        float s1 = s1_raw[i];
        float u = s1 + M2;
        float mi = fmaxf(u, 0.2f * u);   // row max bound (valid: s2[j] <= M2, LReLU monotone)
        row2[i] = make_float2((s1 - mi) * LOG2E, -0.8f * mi * LOG2E);
        s2k[i] = s2_raw[i] * LOG2E;
    }
}

// K3: fused flash-GAT. 256 blocks x 32 rows; 4 waves = 2 rowhalves x 2 colhalves.
__global__ __launch_bounds__(256) void k3_flash(const int* __restrict__ adj,
                                                const unsigned short* __restrict__ hT,
                                                const float* __restrict__ s2k,
                                                const float2* __restrict__ row2,
                                                float* __restrict__ out) {
    int tid = threadIdx.x;
    int w = tid >> 6, lane = tid & 63;
    int c = lane & 15, g = lane >> 4;
    int rh = w >> 1, ch = w & 1;
    int i0 = blockIdx.x * 32;
    int wr = i0 + rh * 16;
    int colbase = ch * 128;
    int sr = wr + c;                      // softmax row this lane computes p for
    float2 rc = row2[sr];
    float a_row = rc.x, m8 = rc.y;
    const int* adjrow = adj + (size_t)sr * N_NODES;
    f32x4 acc[8];
#pragma unroll
    for (int t = 0; t < 8; ++t) acc[t] = (f32x4){0.f, 0.f, 0.f, 0.f};
    float lacc = 0.f;
    for (int j0 = 0; j0 < N_NODES; j0 += 64) {
#pragma unroll
        for (int ks = 0; ks < 2; ++ks) {
            int jb = j0 + ks * 32 + 8 * g;
            int4 ad0 = *(const int4*)(adjrow + jb);
            int4 ad1 = *(const int4*)(adjrow + jb + 4);
            float4 s0 = *(const float4*)(s2k + jb);
            float4 s1v = *(const float4*)(s2k + jb + 4);
            float sv[8] = {s0.x, s0.y, s0.z, s0.w, s1v.x, s1v.y, s1v.z, s1v.w};
            int av[8] = {ad0.x, ad0.y, ad0.z, ad0.w, ad1.x, ad1.y, ad1.z, ad1.w};
            u16x8v au;
#pragma unroll
            for (int e = 0; e < 8; ++e) {
                float v1 = a_row + sv[e];                       // (e-m)*K, pos branch
                float v2 = __builtin_fmaf(v1, 0.2f, m8);        // neg branch
                float arg = fmaxf(v1, v2);                      // <= 0 always
                float pe = __builtin_amdgcn_exp2f(arg);
                float p = (av[e] != 0) ? pe : 0.f;
                lacc += p;
                au[e] = f2bf(p);
            }
            b16x8 af = __builtin_bit_cast(b16x8, au);
#pragma unroll
            for (int t = 0; t < 8; ++t) {
                b16x8 bf = __builtin_bit_cast(b16x8,
                    *(const u16x8v*)(hT + (size_t)(colbase + 16 * t + c) * N_NODES + jb));
                acc[t] = __builtin_amdgcn_mfma_f32_16x16x32_bf16(af, bf, acc[t], 0, 0, 0);
            }
        }
    }
    // row sums: lanes {c, c+16, c+32, c+48} cover all j of row sr
    float l1 = lacc + __shfl_xor(lacc, 16);
    float ltot = l1 + __shfl_xor(l1, 32);
    __shared__ float ldsL[32];
    if ((w == 0 || w == 2) && g == 0) ldsL[rh * 16 + c] = ltot;
    __syncthreads();
#pragma unroll
    for (int r = 0; r < 4; ++r) {
        int lrow = rh * 16 + 4 * g + r;   // C layout: row=(lane>>4)*4+reg
        float lv = ldsL[lrow];
        float inv = (lv > 0.f) ? 1.0f / lv : 0.f;
        int grow = i0 + lrow;
#pragma unroll
        for (int t = 0; t < 8; ++t) {
            float x = acc[t][r] * inv;
            float res = (x > 0.f) ? x : (__builtin_amdgcn_exp2f(x * LOG2E) - 1.0f);
            out[(size_t)grow * OUT_FEAT + colbase + 16 * t + c] = res;
        }
    }
}

extern "C" void kernel_launch(void* const* d_in, const int* in_sizes, int n_in,
                              void* d_out, int out_size, void* d_ws, size_t ws_size,
                              hipStream_t stream) {
    const float* input = (const float*)d_in[0];
    const int* adj = (const int*)d_in[1];
    const float* W = (const float*)d_in[2];
    const float* a_vec = (const float*)d_in[3];
    float* out = (float*)d_out;

    char* ws = (char*)d_ws;
    unsigned short* Wt = (unsigned short*)(ws);                       // 256 KB
    unsigned short* hT = (unsigned short*)(ws + 262144);              // 4 MB
    float* s2k   = (float*)(ws + 262144 + 4194304);                   // 32 KB
    float2* row2 = (float2*)(ws + 262144 + 4194304 + 32768);          // 64 KB
    float* s1_raw = (float*)(ws + 262144 + 4194304 + 32768 + 65536);  // 32 KB
    float* s2_raw = (float*)(ws + 262144 + 4194304 + 32768 + 65536 + 32768); // 32 KB

    hipLaunchKernelGGL(k0_transpose_w, dim3(512), dim3(256), 0, stream, W, Wt);
    hipLaunchKernelGGL(k1_hgemm, dim3(N_NODES / 16), dim3(64), 0, stream,
                       input, Wt, a_vec, hT, s1_raw, s2_raw);
    hipLaunchKernelGGL(k2_prep, dim3(1), dim3(256), 0, stream, s1_raw, s2_raw, s2k, row2);
    hipLaunchKernelGGL(k3_flash, dim3(N_NODES / 32), dim3(256), 0, stream,
                       adj, hT, s2k, row2, out);
}

// Round 2
// 372.728 us; speedup vs baseline: 1.4214x; 1.4214x over previous
//
#include <hip/hip_runtime.h>
#include <stdint.h>

#define N_NODES 8192
#define IN_FEAT 512
#define OUT_FEAT 256
#define LOG2E 1.4426950408889634f

typedef __bf16 b16x8 __attribute__((ext_vector_type(8)));
typedef unsigned short u16x8v __attribute__((ext_vector_type(8)));
typedef float f32x4 __attribute__((ext_vector_type(4)));

static __device__ __forceinline__ unsigned short f2bf(float f) {
    union { float f; uint32_t u; } v; v.f = f;
    uint32_t r = v.u + 0x7FFFu + ((v.u >> 16) & 1u);
    return (unsigned short)(r >> 16);
}

// K0: Wt[c][k] = bf16(W[k][c])  (256 x 512)
__global__ __launch_bounds__(256) void k0_transpose_w(const float* __restrict__ W,
                                                      unsigned short* __restrict__ Wt) {
    int tid = blockIdx.x * 256 + threadIdx.x;   // 0..131071
    int c = tid & (OUT_FEAT - 1);
    int k = tid >> 8;
    Wt[(size_t)c * IN_FEAT + k] = f2bf(W[(size_t)k * OUT_FEAT + c]);
}

// K1: h = X @ W via bf16 MFMA; writes hT bf16 [256][8192] and s1_raw/s2_raw.
// One wave per block, 16 rows x 256 cols, K=512.
__global__ __launch_bounds__(64) void k1_hgemm(const float* __restrict__ input,
                                               const unsigned short* __restrict__ Wt,
                                               const float* __restrict__ a_vec,
                                               unsigned short* __restrict__ hT,
                                               float* __restrict__ s1_raw,
                                               float* __restrict__ s2_raw) {
    int lane = threadIdx.x & 63;
    int c = lane & 15, g = lane >> 4;
    int r0 = blockIdx.x * 16;
    f32x4 acc[16];
#pragma unroll
    for (int t = 0; t < 16; ++t) acc[t] = (f32x4){0.f, 0.f, 0.f, 0.f};
    const float* arow = input + (size_t)(r0 + c) * IN_FEAT;
#pragma unroll 1
    for (int kk = 0; kk < IN_FEAT / 32; ++kk) {
        int kb = kk * 32 + 8 * g;
        float4 x0 = *(const float4*)(arow + kb);
        float4 x1 = *(const float4*)(arow + kb + 4);
        u16x8v au;
        au[0] = f2bf(x0.x); au[1] = f2bf(x0.y); au[2] = f2bf(x0.z); au[3] = f2bf(x0.w);
        au[4] = f2bf(x1.x); au[5] = f2bf(x1.y); au[6] = f2bf(x1.z); au[7] = f2bf(x1.w);
        b16x8 af = __builtin_bit_cast(b16x8, au);
#pragma unroll
        for (int t = 0; t < 16; ++t) {
            b16x8 bf = __builtin_bit_cast(b16x8,
                *(const u16x8v*)(Wt + (size_t)(16 * t + c) * IN_FEAT + kb));
            acc[t] = __builtin_amdgcn_mfma_f32_16x16x32_bf16(af, bf, acc[t], 0, 0, 0);
        }
    }
    // s1 = h@a1, s2 = h@a2 (lane holds rows 4g+r, cols 16t+c)
    float a1v[16], a2v[16];
#pragma unroll
    for (int t = 0; t < 16; ++t) {
        a1v[t] = a_vec[16 * t + c];
        a2v[t] = a_vec[OUT_FEAT + 16 * t + c];
    }
#pragma unroll
    for (int r = 0; r < 4; ++r) {
        float s1p = 0.f, s2p = 0.f;
#pragma unroll
        for (int t = 0; t < 16; ++t) { s1p += acc[t][r] * a1v[t]; s2p += acc[t][r] * a2v[t]; }
#pragma unroll
        for (int m = 1; m <= 8; m <<= 1) { s1p += __shfl_xor(s1p, m); s2p += __shfl_xor(s2p, m); }
        if (c == 0) {
            int row = r0 + 4 * g + r;
            s1_raw[row] = s1p;
            s2_raw[row] = s2p;
        }
    }
    // hT store: 4 consecutive rows per (t): 8B packed
#pragma unroll
    for (int t = 0; t < 16; ++t) {
        ushort4 pk;
        pk.x = f2bf(acc[t][0]); pk.y = f2bf(acc[t][1]);
        pk.z = f2bf(acc[t][2]); pk.w = f2bf(acc[t][3]);
        *(ushort4*)(hT + (size_t)(16 * t + c) * N_NODES + r0 + 4 * g) = pk;
    }
}

// K2: M2 = max(s2); per-row constants a_row=(s1-m)*K, m8=-0.8*m*K; s2k=s2*K
__global__ __launch_bounds__(256) void k2_prep(const float* __restrict__ s1_raw,
                                               const float* __restrict__ s2_raw,
                                               float* __restrict__ s2k,
                                               float2* __restrict__ row2) {
    __shared__ float red[256];
    int tid = threadIdx.x;
    float m = -3.0e38f;
    for (int j = tid; j < N_NODES; j += 256) m = fmaxf(m, s2_raw[j]);
    red[tid] = m;
    __syncthreads();
    for (int s = 128; s > 0; s >>= 1) {
        if (tid < s) red[tid] = fmaxf(red[tid], red[tid + s]);
        __syncthreads();
    }
    float M2 = red[0];
    for (int i = tid; i < N_NODES; i += 256) {
        float s1 = s1_raw[i];
        float u = s1 + M2;
        float mi = fmaxf(u, 0.2f * u);   // row max bound (valid: s2[j] <= M2, LReLU monotone)
        row2[i] = make_float2((s1 - mi) * LOG2E, -0.8f * mi * LOG2E);
        s2k[i] = s2_raw[i] * LOG2E;
    }
}

// K3 v2: fused flash-GAT, occupancy-oriented.
// 512 blocks x 512 threads (8 waves). Block owns 16 rows.
// wave w: ch = w&1 (col half, 128 cols), jq = w>>1 (j quarter, 2048 js).
// Cross-wave j-reduction via LDS (one barrier).
__global__ __launch_bounds__(512, 2) void k3_flash(const int* __restrict__ adj,
                                                   const unsigned short* __restrict__ hT,
                                                   const float* __restrict__ s2k,
                                                   const float2* __restrict__ row2,
                                                   float* __restrict__ out) {
    __shared__ float redAcc[6 * 2048];   // 48 KB: waves w=2..7 stage acc here
    __shared__ float ldsL[64];           // [jq][row] quarter row-sums (ch==0 only)

    int tid = threadIdx.x;
    int w = tid >> 6, lane = tid & 63;
    int c = lane & 15, g = lane >> 4;
    int ch = w & 1, jq = w >> 1;
    int i0 = blockIdx.x * 16;
    int colbase = ch * 128;
    int sr = i0 + c;                     // softmax row this lane computes p for
    float2 rc = row2[sr];
    float a_row = rc.x, m8 = rc.y;
    const int* adjrow = adj + (size_t)sr * N_NODES;
    int jbase = jq * (N_NODES / 4);

    f32x4 acc[8];
#pragma unroll
    for (int t = 0; t < 8; ++t) acc[t] = (f32x4){0.f, 0.f, 0.f, 0.f};
    float lacc = 0.f;

#pragma unroll 1
    for (int j0 = jbase; j0 < jbase + N_NODES / 4; j0 += 64) {
#pragma unroll
        for (int ks = 0; ks < 2; ++ks) {
            int jb = j0 + ks * 32 + 8 * g;
            int4 ad0 = *(const int4*)(adjrow + jb);
            int4 ad1 = *(const int4*)(adjrow + jb + 4);
            float4 s0 = *(const float4*)(s2k + jb);
            float4 s1v = *(const float4*)(s2k + jb + 4);
            float sv[8] = {s0.x, s0.y, s0.z, s0.w, s1v.x, s1v.y, s1v.z, s1v.w};
            int av[8] = {ad0.x, ad0.y, ad0.z, ad0.w, ad1.x, ad1.y, ad1.z, ad1.w};
            b16x8 af;
#pragma unroll
            for (int e = 0; e < 8; ++e) {
                float v1 = a_row + sv[e];                       // (e-m)*K, pos branch
                float v2 = __builtin_fmaf(v1, 0.2f, m8);        // neg branch
                float arg = fmaxf(v1, v2);                      // <= 0 always
                float pe = __builtin_amdgcn_exp2f(arg);
                float p = (av[e] != 0) ? pe : 0.f;
                lacc += p;
                af[e] = (__bf16)p;                              // v_cvt_pk_bf16_f32
            }
#pragma unroll
            for (int t = 0; t < 8; ++t) {
                b16x8 bf = __builtin_bit_cast(b16x8,
                    *(const u16x8v*)(hT + (size_t)(colbase + 16 * t + c) * N_NODES + jb));
                acc[t] = __builtin_amdgcn_mfma_f32_16x16x32_bf16(af, bf, acc[t], 0, 0, 0);
            }
        }
    }

    // quarter row-sums: lanes {c, c+16, c+32, c+48} cover all j of row sr in this quarter
    float l1 = lacc + __shfl_xor(lacc, 16);
    float ltot = l1 + __shfl_xor(l1, 32);
    if (ch == 0 && g == 0) ldsL[jq * 16 + c] = ltot;

    if (w >= 2) {
        float* reg = redAcc + (w - 2) * 2048;
#pragma unroll
        for (int t = 0; t < 8; ++t)
            *(f32x4*)(reg + (t * 64 + lane) * 4) = acc[t];
    }
    __syncthreads();
    if (w < 2) {
#pragma unroll
        for (int src = 0; src < 3; ++src) {
            float* reg = redAcc + (src * 2 + ch) * 2048;  // writer w = 2+2*src+ch
#pragma unroll
            for (int t = 0; t < 8; ++t)
                acc[t] += *(const f32x4*)(reg + (t * 64 + lane) * 4);
        }
#pragma unroll
        for (int r = 0; r < 4; ++r) {
            int lrow = 4 * g + r;                         // C layout: row=(lane>>4)*4+reg
            float lv = ldsL[lrow] + ldsL[16 + lrow] + ldsL[32 + lrow] + ldsL[48 + lrow];
            float inv = (lv > 0.f) ? 1.0f / lv : 0.f;
            int grow = i0 + lrow;
#pragma unroll
            for (int t = 0; t < 8; ++t) {
                float x = acc[t][r] * inv;
                float res = (x > 0.f) ? x : (__builtin_amdgcn_exp2f(x * LOG2E) - 1.0f);
                out[(size_t)grow * OUT_FEAT + colbase + 16 * t + c] = res;
            }
        }
    }
}

extern "C" void kernel_launch(void* const* d_in, const int* in_sizes, int n_in,
                              void* d_out, int out_size, void* d_ws, size_t ws_size,
                              hipStream_t stream) {
    const float* input = (const float*)d_in[0];
    const int* adj = (const int*)d_in[1];
    const float* W = (const float*)d_in[2];
    const float* a_vec = (const float*)d_in[3];
    float* out = (float*)d_out;

    char* ws = (char*)d_ws;
    unsigned short* Wt = (unsigned short*)(ws);                       // 256 KB
    unsigned short* hT = (unsigned short*)(ws + 262144);              // 4 MB
    float* s2k   = (float*)(ws + 262144 + 4194304);                   // 32 KB
    float2* row2 = (float2*)(ws + 262144 + 4194304 + 32768);          // 64 KB
    float* s1_raw = (float*)(ws + 262144 + 4194304 + 32768 + 65536);  // 32 KB
    float* s2_raw = (float*)(ws + 262144 + 4194304 + 32768 + 65536 + 32768); // 32 KB

    hipLaunchKernelGGL(k0_transpose_w, dim3(512), dim3(256), 0, stream, W, Wt);
    hipLaunchKernelGGL(k1_hgemm, dim3(N_NODES / 16), dim3(64), 0, stream,
                       input, Wt, a_vec, hT, s1_raw, s2_raw);
    hipLaunchKernelGGL(k2_prep, dim3(1), dim3(256), 0, stream, s1_raw, s2_raw, s2k, row2);
    hipLaunchKernelGGL(k3_flash, dim3(N_NODES / 16), dim3(512), 0, stream,
                       adj, hT, s2k, row2, out);
}

// Round 3
// 242.912 us; speedup vs baseline: 2.1810x; 1.5344x over previous
//
#include <hip/hip_runtime.h>
#include <stdint.h>

#define N_NODES 8192
#define IN_FEAT 512
#define OUT_FEAT 256
#define LOG2E 1.4426950408889634f

typedef __bf16 b16x8 __attribute__((ext_vector_type(8)));
typedef unsigned short u16x8v __attribute__((ext_vector_type(8)));
typedef float f32x4 __attribute__((ext_vector_type(4)));

static __device__ __forceinline__ unsigned short f2bf(float f) {
    union { float f; uint32_t u; } v; v.f = f;
    uint32_t r = v.u + 0x7FFFu + ((v.u >> 16) & 1u);
    return (unsigned short)(r >> 16);
}

// K_pack: adj int32 [8192][8192] -> bitmask, 1 bit per entry (8 MB).
// Each thread: 8 ints (32 B contiguous) -> 1 byte. Fully coalesced.
__global__ __launch_bounds__(256) void k_pack(const int* __restrict__ adj,
                                              unsigned char* __restrict__ bits) {
    size_t t = (size_t)blockIdx.x * 256 + threadIdx.x;
    const int4* a4 = (const int4*)adj + t * 2;
    int4 x0 = a4[0];
    int4 x1 = a4[1];
    unsigned b = (unsigned)(x0.x != 0)
               | ((unsigned)(x0.y != 0) << 1)
               | ((unsigned)(x0.z != 0) << 2)
               | ((unsigned)(x0.w != 0) << 3)
               | ((unsigned)(x1.x != 0) << 4)
               | ((unsigned)(x1.y != 0) << 5)
               | ((unsigned)(x1.z != 0) << 6)
               | ((unsigned)(x1.w != 0) << 7);
    bits[t] = (unsigned char)b;
}

// K0: Wt[c][k] = bf16(W[k][c])  (256 x 512)
__global__ __launch_bounds__(256) void k0_transpose_w(const float* __restrict__ W,
                                                      unsigned short* __restrict__ Wt) {
    int tid = blockIdx.x * 256 + threadIdx.x;   // 0..131071
    int c = tid & (OUT_FEAT - 1);
    int k = tid >> 8;
    Wt[(size_t)c * IN_FEAT + k] = f2bf(W[(size_t)k * OUT_FEAT + c]);
}

// K1: h = X @ W via bf16 MFMA. Writes hTf in MFMA-B-fragment order:
// hTf[((chunk*16 + t)*64 + lane)*8 + e] = bf16(h[j = chunk*32 + (lane>>4)*8 + e][col = t*16 + (lane&15)])
// Also s1_raw/s2_raw. 4 waves/block, each wave owns 16 rows (j's).
__global__ __launch_bounds__(256) void k1_hgemm(const float* __restrict__ input,
                                                const unsigned short* __restrict__ Wt,
                                                const float* __restrict__ a_vec,
                                                unsigned short* __restrict__ hTf,
                                                float* __restrict__ s1_raw,
                                                float* __restrict__ s2_raw) {
    int tid = threadIdx.x;
    int lane = tid & 63;
    int c = lane & 15, g = lane >> 4;
    int r0 = blockIdx.x * 64 + (tid >> 6) * 16;
    f32x4 acc[16];
#pragma unroll
    for (int t = 0; t < 16; ++t) acc[t] = (f32x4){0.f, 0.f, 0.f, 0.f};
    const float* arow = input + (size_t)(r0 + c) * IN_FEAT;
#pragma unroll 1
    for (int kk = 0; kk < IN_FEAT / 32; ++kk) {
        int kb = kk * 32 + 8 * g;
        float4 x0 = *(const float4*)(arow + kb);
        float4 x1 = *(const float4*)(arow + kb + 4);
        u16x8v au;
        au[0] = f2bf(x0.x); au[1] = f2bf(x0.y); au[2] = f2bf(x0.z); au[3] = f2bf(x0.w);
        au[4] = f2bf(x1.x); au[5] = f2bf(x1.y); au[6] = f2bf(x1.z); au[7] = f2bf(x1.w);
        b16x8 af = __builtin_bit_cast(b16x8, au);
#pragma unroll
        for (int t = 0; t < 16; ++t) {
            b16x8 bf = __builtin_bit_cast(b16x8,
                *(const u16x8v*)(Wt + (size_t)(16 * t + c) * IN_FEAT + kb));
            acc[t] = __builtin_amdgcn_mfma_f32_16x16x32_bf16(af, bf, acc[t], 0, 0, 0);
        }
    }
    // s1 = h@a1, s2 = h@a2 (lane holds rows r0+4g+r, cols 16t+c)
    float a1v[16], a2v[16];
#pragma unroll
    for (int t = 0; t < 16; ++t) {
        a1v[t] = a_vec[16 * t + c];
        a2v[t] = a_vec[OUT_FEAT + 16 * t + c];
    }
#pragma unroll
    for (int r = 0; r < 4; ++r) {
        float s1p = 0.f, s2p = 0.f;
#pragma unroll
        for (int t = 0; t < 16; ++t) { s1p += acc[t][r] * a1v[t]; s2p += acc[t][r] * a2v[t]; }
#pragma unroll
        for (int m = 1; m <= 8; m <<= 1) { s1p += __shfl_xor(s1p, m); s2p += __shfl_xor(s2p, m); }
        if (c == 0) {
            int row = r0 + 4 * g + r;
            s1_raw[row] = s1p;
            s2_raw[row] = s2p;
        }
    }
    // hTf store: fragment order. j = r0+4g+r; chunk = r0>>5; jj = j&31;
    // lane' = (jj>>3)*16 + c; e = jj&7 = 4*(g&1)+r. Stores are contiguous per wave.
    int chunk = r0 >> 5;
    int lp = ((r0 & 16) >> 3) + (g >> 1);     // jj>>3
    int e0 = 4 * (g & 1);
#pragma unroll
    for (int t = 0; t < 16; ++t) {
        ushort4 pk;
        pk.x = f2bf(acc[t][0]); pk.y = f2bf(acc[t][1]);
        pk.z = f2bf(acc[t][2]); pk.w = f2bf(acc[t][3]);
        *(ushort4*)(hTf + ((size_t)(chunk * 16 + t) * 64 + lp * 16 + c) * 8 + e0) = pk;
    }
}

// K2: M2 = max(s2); per-row constants a_row=(s1-m)*K, m8=-0.8*m*K; s2k=s2*K
// 32 blocks; each computes the full max redundantly, handles 256 rows.
__global__ __launch_bounds__(256) void k2_prep(const float* __restrict__ s1_raw,
                                               const float* __restrict__ s2_raw,
                                               float* __restrict__ s2k,
                                               float2* __restrict__ row2) {
    __shared__ float red[256];
    int tid = threadIdx.x;
    float m = -3.0e38f;
    for (int j = tid; j < N_NODES; j += 256) m = fmaxf(m, s2_raw[j]);
    red[tid] = m;
    __syncthreads();
    for (int s = 128; s > 0; s >>= 1) {
        if (tid < s) red[tid] = fmaxf(red[tid], red[tid + s]);
        __syncthreads();
    }
    float M2 = red[0];
    int i = blockIdx.x * 256 + tid;
    float s1 = s1_raw[i];
    float u = s1 + M2;
    float mi = fmaxf(u, 0.2f * u);   // row max bound (valid: s2[j] <= M2, LReLU monotone)
    row2[i] = make_float2((s1 - mi) * LOG2E, -0.8f * mi * LOG2E);
    s2k[i] = s2_raw[i] * LOG2E;
}

// K3: fused flash-GAT. 512 blocks x 512 threads (8 waves), block owns 16 rows.
// wave w: ch = w&1 (col half: 8 tiles), jq = w>>1 (j quarter, 2048 js).
// adj mask staged in LDS (pitch 260 dwords -> 2-way bank alias, free).
// hTf b-frags: contiguous 1KB wave-loads, L2-resident.
// LDS union: mask (16.6 KB, loop phase) / redAcc (48 KB, epilogue phase).
__global__ __launch_bounds__(512, 4) void k3_flash(const int* __restrict__ bits,
                                                   const unsigned short* __restrict__ hTf,
                                                   const float* __restrict__ s2k,
                                                   const float2* __restrict__ row2,
                                                   float* __restrict__ out) {
    __shared__ int4 smem4[3088];                 // 49408 B: union(mask 16640, redAcc 49152) + ldsL 256
    uint32_t* msk = (uint32_t*)smem4;            // [16][260] dwords, pitch 260
    float* redAcc = (float*)smem4;               // 6 waves * 2048 floats
    float* ldsL = (float*)smem4 + 12288;         // [4][16] quarter row-sums

    int tid = threadIdx.x;
    int w = tid >> 6, lane = tid & 63;
    int c = lane & 15, g = lane >> 4;
    int ch = w & 1, jq = w >> 1;
    int i0 = blockIdx.x * 16;

    // stage 16 rows x 256 dwords of adj bitmask into LDS (coalesced, 1 row per wave per pass)
#pragma unroll
    for (int p = 0; p < 2; ++p) {
        int rr = p * 8 + w;
        int dw4 = (tid & 63) * 4;
        int4 v = *(const int4*)(bits + (size_t)(i0 + rr) * 256 + dw4);
        *(int4*)(msk + rr * 260 + dw4) = v;
    }
    __syncthreads();

    float2 rc = row2[i0 + c];
    float a_row = rc.x, m8 = rc.y;
    const uint32_t* mrow = msk + c * 260;

    f32x4 acc[8];
#pragma unroll
    for (int t = 0; t < 8; ++t) acc[t] = (f32x4){0.f, 0.f, 0.f, 0.f};
    float lacc = 0.f;

#pragma unroll 2
    for (int kk = 0; kk < 64; ++kk) {
        int jchunk = jq * 64 + kk;
        uint32_t md = mrow[jchunk];                    // ds_read_b32, 4-lane broadcast
        uint32_t mb = (md >> (8 * g)) & 0xFFu;         // this lane's 8 adjacency bits
        int jb = jchunk * 32 + 8 * g;
        float4 s0 = *(const float4*)(s2k + jb);
        float4 s1v = *(const float4*)(s2k + jb + 4);
        float sv[8] = {s0.x, s0.y, s0.z, s0.w, s1v.x, s1v.y, s1v.z, s1v.w};
        b16x8 af;
#pragma unroll
        for (int e = 0; e < 8; ++e) {
            float v1 = a_row + sv[e];                  // (e-m)*log2e, pos branch
            float v2 = __builtin_fmaf(v1, 0.2f, m8);   // neg branch
            float arg = fmaxf(v1, v2);                 // <= 0 always
            float pe = __builtin_amdgcn_exp2f(arg);
            float p = (mb & (1u << e)) ? pe : 0.f;
            lacc += p;
            af[e] = (__bf16)p;
        }
        const unsigned short* bbase = hTf + ((size_t)jchunk * 16 + ch * 8) * 512;
#pragma unroll
        for (int t = 0; t < 8; ++t) {
            b16x8 bf = __builtin_bit_cast(b16x8, *(const u16x8v*)(bbase + (t * 64 + lane) * 8));
            acc[t] = __builtin_amdgcn_mfma_f32_16x16x32_bf16(af, bf, acc[t], 0, 0, 0);
        }
    }

    // quarter row-sums: lanes {c, c+16, c+32, c+48} cover all j of row i0+c in this quarter
    float l1 = lacc + __shfl_xor(lacc, 16);
    float ltot = l1 + __shfl_xor(l1, 32);
    if (ch == 0 && g == 0) ldsL[jq * 16 + c] = ltot;
    __syncthreads();                                   // mask phase over; redAcc may now overwrite

    if (w >= 2) {
        float* reg = redAcc + (w - 2) * 2048;
#pragma unroll
        for (int t = 0; t < 8; ++t)
            *(f32x4*)(reg + (t * 64 + lane) * 4) = acc[t];
    }
    __syncthreads();
    if (w < 2) {
#pragma unroll
        for (int src = 0; src < 3; ++src) {
            float* reg = redAcc + (src * 2 + ch) * 2048;  // writer w = 2+2*src+ch
#pragma unroll
            for (int t = 0; t < 8; ++t)
                acc[t] += *(const f32x4*)(reg + (t * 64 + lane) * 4);
        }
#pragma unroll
        for (int r = 0; r < 4; ++r) {
            int lrow = 4 * g + r;                      // C layout: row=(lane>>4)*4+reg
            float lv = ldsL[lrow] + ldsL[16 + lrow] + ldsL[32 + lrow] + ldsL[48 + lrow];
            float inv = (lv > 0.f) ? 1.0f / lv : 0.f;
            int grow = i0 + lrow;
#pragma unroll
            for (int t = 0; t < 8; ++t) {
                float x = acc[t][r] * inv;
                float res = (x > 0.f) ? x : (__builtin_amdgcn_exp2f(x * LOG2E) - 1.0f);
                out[(size_t)grow * OUT_FEAT + ch * 128 + 16 * t + c] = res;
            }
        }
    }
}

extern "C" void kernel_launch(void* const* d_in, const int* in_sizes, int n_in,
                              void* d_out, int out_size, void* d_ws, size_t ws_size,
                              hipStream_t stream) {
    const float* input = (const float*)d_in[0];
    const int* adj = (const int*)d_in[1];
    const float* W = (const float*)d_in[2];
    const float* a_vec = (const float*)d_in[3];
    float* out = (float*)d_out;

    char* ws = (char*)d_ws;
    unsigned short* Wt = (unsigned short*)(ws);                        // 256 KB
    unsigned short* hTf = (unsigned short*)(ws + 262144);              // 4 MB
    float* s2k    = (float*)(ws + 4456448);                            // 32 KB
    float2* row2  = (float2*)(ws + 4489216);                           // 64 KB
    float* s1_raw = (float*)(ws + 4554752);                            // 32 KB
    float* s2_raw = (float*)(ws + 4587520);                            // 32 KB
    unsigned char* bits = (unsigned char*)(ws + 4620288);              // 8 MB

    hipLaunchKernelGGL(k_pack, dim3(32768), dim3(256), 0, stream, adj, bits);
    hipLaunchKernelGGL(k0_transpose_w, dim3(512), dim3(256), 0, stream, W, Wt);
    hipLaunchKernelGGL(k1_hgemm, dim3(N_NODES / 64), dim3(256), 0, stream,
                       input, Wt, a_vec, hTf, s1_raw, s2_raw);
    hipLaunchKernelGGL(k2_prep, dim3(32), dim3(256), 0, stream, s1_raw, s2_raw, s2k, row2);
    hipLaunchKernelGGL(k3_flash, dim3(N_NODES / 16), dim3(512), 0, stream,
                       (const int*)bits, hTf, s2k, row2, out);
}

// Round 4
// 218.964 us; speedup vs baseline: 2.4195x; 1.1094x over previous
//
#include <hip/hip_runtime.h>
#include <stdint.h>

#define N_NODES 8192
#define IN_FEAT 512
#define OUT_FEAT 256
#define LOG2E 1.4426950408889634f

typedef __bf16 b16x8 __attribute__((ext_vector_type(8)));
typedef unsigned short u16x8v __attribute__((ext_vector_type(8)));
typedef float f32x4 __attribute__((ext_vector_type(4)));

static __device__ __forceinline__ unsigned short f2bf(float f) {
    union { float f; uint32_t u; } v; v.f = f;
    uint32_t r = v.u + 0x7FFFu + ((v.u >> 16) & 1u);
    return (unsigned short)(r >> 16);
}

// K_pack: adj int32 [8192][8192] -> TRANSPOSED bitmask bitsT[jchunk][row].
// bit b of bitsT[jc*8192 + i] = (adj[i][jc*32 + b] != 0).
// Thread: one (row, chunk): 32 ints = 128 B fully-used lines; writes coalesced
// (64 consecutive dwords per wave). grid (128, 64), block 256.
__global__ __launch_bounds__(256) void k_pack(const int* __restrict__ adj,
                                              uint32_t* __restrict__ bitsT) {
    int tid = threadIdx.x;
    int lane = tid & 63, w = tid >> 6;
    int i = blockIdx.x * 64 + lane;
    int jc = blockIdx.y * 4 + w;
    const int4* src = (const int4*)(adj + (size_t)i * N_NODES + jc * 32);
    uint32_t m = 0;
#pragma unroll
    for (int q = 0; q < 8; ++q) {
        int4 v = src[q];
        m |= ((uint32_t)(v.x != 0) << (4 * q))
           | ((uint32_t)(v.y != 0) << (4 * q + 1))
           | ((uint32_t)(v.z != 0) << (4 * q + 2))
           | ((uint32_t)(v.w != 0) << (4 * q + 3));
    }
    bitsT[(size_t)jc * N_NODES + i] = m;
}

// K0: Wt[c][k] = bf16(W[k][c])  (256 x 512)
__global__ __launch_bounds__(256) void k0_transpose_w(const float* __restrict__ W,
                                                      unsigned short* __restrict__ Wt) {
    int tid = blockIdx.x * 256 + threadIdx.x;
    int c = tid & (OUT_FEAT - 1);
    int k = tid >> 8;
    Wt[(size_t)c * IN_FEAT + k] = f2bf(W[(size_t)k * OUT_FEAT + c]);
}

// K1: h = X @ W via bf16 MFMA. Writes hTf in MFMA-B-fragment order:
// hTf[((chunk*16 + t)*64 + lane)*8 + e] = bf16(h[chunk*32 + (lane>>4)*8 + e][16t + (lane&15)])
// Also s1_raw/s2_raw. 4 waves/block, each wave owns 16 rows.
__global__ __launch_bounds__(256) void k1_hgemm(const float* __restrict__ input,
                                                const unsigned short* __restrict__ Wt,
                                                const float* __restrict__ a_vec,
                                                unsigned short* __restrict__ hTf,
                                                float* __restrict__ s1_raw,
                                                float* __restrict__ s2_raw) {
    int tid = threadIdx.x;
    int lane = tid & 63;
    int c = lane & 15, g = lane >> 4;
    int r0 = blockIdx.x * 64 + (tid >> 6) * 16;
    f32x4 acc[16];
#pragma unroll
    for (int t = 0; t < 16; ++t) acc[t] = (f32x4){0.f, 0.f, 0.f, 0.f};
    const float* arow = input + (size_t)(r0 + c) * IN_FEAT;
#pragma unroll 1
    for (int kk = 0; kk < IN_FEAT / 32; ++kk) {
        int kb = kk * 32 + 8 * g;
        float4 x0 = *(const float4*)(arow + kb);
        float4 x1 = *(const float4*)(arow + kb + 4);
        u16x8v au;
        au[0] = f2bf(x0.x); au[1] = f2bf(x0.y); au[2] = f2bf(x0.z); au[3] = f2bf(x0.w);
        au[4] = f2bf(x1.x); au[5] = f2bf(x1.y); au[6] = f2bf(x1.z); au[7] = f2bf(x1.w);
        b16x8 af = __builtin_bit_cast(b16x8, au);
#pragma unroll
        for (int t = 0; t < 16; ++t) {
            b16x8 bf = __builtin_bit_cast(b16x8,
                *(const u16x8v*)(Wt + (size_t)(16 * t + c) * IN_FEAT + kb));
            acc[t] = __builtin_amdgcn_mfma_f32_16x16x32_bf16(af, bf, acc[t], 0, 0, 0);
        }
    }
    float a1v[16], a2v[16];
#pragma unroll
    for (int t = 0; t < 16; ++t) {
        a1v[t] = a_vec[16 * t + c];
        a2v[t] = a_vec[OUT_FEAT + 16 * t + c];
    }
#pragma unroll
    for (int r = 0; r < 4; ++r) {
        float s1p = 0.f, s2p = 0.f;
#pragma unroll
        for (int t = 0; t < 16; ++t) { s1p += acc[t][r] * a1v[t]; s2p += acc[t][r] * a2v[t]; }
#pragma unroll
        for (int m = 1; m <= 8; m <<= 1) { s1p += __shfl_xor(s1p, m); s2p += __shfl_xor(s2p, m); }
        if (c == 0) {
            int row = r0 + 4 * g + r;
            s1_raw[row] = s1p;
            s2_raw[row] = s2p;
        }
    }
    int chunk = r0 >> 5;
    int lp = ((r0 & 16) >> 3) + (g >> 1);
    int e0 = 4 * (g & 1);
#pragma unroll
    for (int t = 0; t < 16; ++t) {
        ushort4 pk;
        pk.x = f2bf(acc[t][0]); pk.y = f2bf(acc[t][1]);
        pk.z = f2bf(acc[t][2]); pk.w = f2bf(acc[t][3]);
        *(ushort4*)(hTf + ((size_t)(chunk * 16 + t) * 64 + lp * 16 + c) * 8 + e0) = pk;
    }
}

// K2: M2 = max(s2); per-row constants a_row=(s1-m)*K, m8=-0.8*m*K; s2k=s2*K
__global__ __launch_bounds__(256) void k2_prep(const float* __restrict__ s1_raw,
                                               const float* __restrict__ s2_raw,
                                               float* __restrict__ s2k,
                                               float2* __restrict__ row2) {
    __shared__ float red[256];
    int tid = threadIdx.x;
    float m = -3.0e38f;
    for (int j = tid; j < N_NODES; j += 256) m = fmaxf(m, s2_raw[j]);
    red[tid] = m;
    __syncthreads();
    for (int s = 128; s > 0; s >>= 1) {
        if (tid < s) red[tid] = fmaxf(red[tid], red[tid + s]);
        __syncthreads();
    }
    float M2 = red[0];
    int i = blockIdx.x * 256 + tid;
    float s1 = s1_raw[i];
    float u = s1 + M2;
    float mi = fmaxf(u, 0.2f * u);
    row2[i] = make_float2((s1 - mi) * LOG2E, -0.8f * mi * LOG2E);
    s2k[i] = s2_raw[i] * LOG2E;
}

// K3: fused flash-GAT partials. Grid 512 = 128 row-groups (64 rows) x 4 j-quarters
// (jq = blockIdx.x & 3 -> constant per XCD: L2-resident hTf quarter).
// 8 waves: (rq 0..3) x (ch 0..1); wave owns 16 rows x 128 cols, iterates 64 chunks.
// No LDS, no barriers. Emits unnormalized pout[jq][row][col] + rowpart[jq][row].
__global__ __launch_bounds__(512, 4) void k3_flash(const uint32_t* __restrict__ bitsT,
                                                   const unsigned short* __restrict__ hTf,
                                                   const float* __restrict__ s2k,
                                                   const float2* __restrict__ row2,
                                                   float* __restrict__ pout,
                                                   float* __restrict__ rowpart) {
    int tid = threadIdx.x;
    int w = tid >> 6, lane = tid & 63;
    int c = lane & 15, g = lane >> 4;
    int ch = w & 1, rq = w >> 1;
    int jq = blockIdx.x & 3;
    int rg = blockIdx.x >> 2;
    int row16 = rg * 64 + rq * 16;       // this wave's 16 rows

    float2 rc = row2[row16 + c];
    float a_row = rc.x, m8 = rc.y;

    f32x4 acc[8];
#pragma unroll
    for (int t = 0; t < 8; ++t) acc[t] = (f32x4){0.f, 0.f, 0.f, 0.f};
    float lacc = 0.f;

#pragma unroll 2
    for (int kk = 0; kk < 64; ++kk) {
        int jchunk = jq * 64 + kk;
        uint32_t md = bitsT[(size_t)jchunk * N_NODES + row16 + c];  // 64B line, g-broadcast
        uint32_t mb = (md >> (8 * g)) & 0xFFu;
        int jb = jchunk * 32 + 8 * g;
        float4 s0 = *(const float4*)(s2k + jb);
        float4 s1v = *(const float4*)(s2k + jb + 4);
        float sv[8] = {s0.x, s0.y, s0.z, s0.w, s1v.x, s1v.y, s1v.z, s1v.w};
        b16x8 af;
#pragma unroll
        for (int e = 0; e < 8; ++e) {
            float v1 = a_row + sv[e];                  // (e-m)*log2e, pos branch
            float v2 = __builtin_fmaf(v1, 0.2f, m8);   // neg branch
            float arg = fmaxf(v1, v2);                 // <= 0 always
            float pe = __builtin_amdgcn_exp2f(arg);
            float p = (mb & (1u << e)) ? pe : 0.f;
            lacc += p;
            af[e] = (__bf16)p;
        }
        const unsigned short* bbase = hTf + ((size_t)jchunk * 16 + ch * 8) * 512;
#pragma unroll
        for (int t = 0; t < 8; ++t) {
            b16x8 bf = __builtin_bit_cast(b16x8, *(const u16x8v*)(bbase + (t * 64 + lane) * 8));
            acc[t] = __builtin_amdgcn_mfma_f32_16x16x32_bf16(af, bf, acc[t], 0, 0, 0);
        }
    }

    // partial row sums over this j-quarter (lanes c,c+16,c+32,c+48 cover all g-octets)
    float l1 = lacc + __shfl_xor(lacc, 16);
    float ltot = l1 + __shfl_xor(l1, 32);
    if (ch == 0 && g == 0) rowpart[jq * N_NODES + row16 + c] = ltot;

#pragma unroll
    for (int r = 0; r < 4; ++r) {
        int grow = row16 + 4 * g + r;                  // C layout: row=(lane>>4)*4+r
#pragma unroll
        for (int t = 0; t < 8; ++t) {
            pout[((size_t)jq * N_NODES + grow) * OUT_FEAT + ch * 128 + 16 * t + c] = acc[t][r];
        }
    }
}

// K4: out = elu( (sum_q pout[q]) / (sum_q rowpart[q]) ). Coalesced, 2M threads.
__global__ __launch_bounds__(256) void k4_reduce(const float* __restrict__ pout,
                                                 const float* __restrict__ rowpart,
                                                 float* __restrict__ out) {
    int t = blockIdx.x * 256 + threadIdx.x;
    int row = t >> 8;
    float s = 0.f, l = 0.f;
#pragma unroll
    for (int q = 0; q < 4; ++q) {
        s += pout[(size_t)q * N_NODES * OUT_FEAT + t];
        l += rowpart[q * N_NODES + row];
    }
    float inv = (l > 0.f) ? 1.0f / l : 0.f;
    float x = s * inv;
    out[t] = (x > 0.f) ? x : (__builtin_amdgcn_exp2f(x * LOG2E) - 1.0f);
}

extern "C" void kernel_launch(void* const* d_in, const int* in_sizes, int n_in,
                              void* d_out, int out_size, void* d_ws, size_t ws_size,
                              hipStream_t stream) {
    const float* input = (const float*)d_in[0];
    const int* adj = (const int*)d_in[1];
    const float* W = (const float*)d_in[2];
    const float* a_vec = (const float*)d_in[3];
    float* out = (float*)d_out;

    char* ws = (char*)d_ws;
    unsigned short* Wt  = (unsigned short*)(ws);                 // 256 KB
    unsigned short* hTf = (unsigned short*)(ws + 262144);        // 4 MB
    float*  s2k     = (float*)(ws + 4456448);                    // 32 KB
    float2* row2    = (float2*)(ws + 4489216);                   // 64 KB
    float*  s1_raw  = (float*)(ws + 4554752);                    // 32 KB
    float*  s2_raw  = (float*)(ws + 4587520);                    // 32 KB
    uint32_t* bitsT = (uint32_t*)(ws + 4620288);                 // 8 MB
    float*  rowpart = (float*)(ws + 13008896);                   // 128 KB
    float*  pout    = (float*)(ws + 13139968);                   // 32 MB

    hipLaunchKernelGGL(k_pack, dim3(128, 64), dim3(256), 0, stream, adj, bitsT);
    hipLaunchKernelGGL(k0_transpose_w, dim3(512), dim3(256), 0, stream, W, Wt);
    hipLaunchKernelGGL(k1_hgemm, dim3(N_NODES / 64), dim3(256), 0, stream,
                       input, Wt, a_vec, hTf, s1_raw, s2_raw);
    hipLaunchKernelGGL(k2_prep, dim3(32), dim3(256), 0, stream, s1_raw, s2_raw, s2k, row2);
    hipLaunchKernelGGL(k3_flash, dim3(512), dim3(512), 0, stream,
                       bitsT, hTf, s2k, row2, pout, rowpart);
    hipLaunchKernelGGL(k4_reduce, dim3(N_NODES * OUT_FEAT / 256), dim3(256), 0, stream,
                       pout, rowpart, out);
}

// Round 5
// 207.050 us; speedup vs baseline: 2.5587x; 1.0575x over previous
//
#include <hip/hip_runtime.h>
#include <stdint.h>

#define N_NODES 8192
#define IN_FEAT 512
#define OUT_FEAT 256
#define LOG2E 1.4426950408889634f

typedef __bf16 b16x8 __attribute__((ext_vector_type(8)));
typedef unsigned short u16x8v __attribute__((ext_vector_type(8)));
typedef float f32x4 __attribute__((ext_vector_type(4)));

static __device__ __forceinline__ unsigned short f2bf(float f) {
    union { float f; uint32_t u; } v; v.f = f;
    uint32_t r = v.u + 0x7FFFu + ((v.u >> 16) & 1u);
    return (unsigned short)(r >> 16);
}

// K_pack: adj int32 [8192][8192] -> TRANSPOSED bitmask bitsT[jchunk][row].
__global__ __launch_bounds__(256) void k_pack(const int* __restrict__ adj,
                                              uint32_t* __restrict__ bitsT) {
    int tid = threadIdx.x;
    int lane = tid & 63, w = tid >> 6;
    int i = blockIdx.x * 64 + lane;
    int jc = blockIdx.y * 4 + w;
    const int4* src = (const int4*)(adj + (size_t)i * N_NODES + jc * 32);
    uint32_t m = 0;
#pragma unroll
    for (int q = 0; q < 8; ++q) {
        int4 v = src[q];
        m |= ((uint32_t)(v.x != 0) << (4 * q))
           | ((uint32_t)(v.y != 0) << (4 * q + 1))
           | ((uint32_t)(v.z != 0) << (4 * q + 2))
           | ((uint32_t)(v.w != 0) << (4 * q + 3));
    }
    bitsT[(size_t)jc * N_NODES + i] = m;
}

// K0: Wt[c][k] = bf16(W[k][c])  (256 x 512)
__global__ __launch_bounds__(256) void k0_transpose_w(const float* __restrict__ W,
                                                      unsigned short* __restrict__ Wt) {
    int tid = blockIdx.x * 256 + threadIdx.x;
    int c = tid & (OUT_FEAT - 1);
    int k = tid >> 8;
    Wt[(size_t)c * IN_FEAT + k] = f2bf(W[(size_t)k * OUT_FEAT + c]);
}

// K1: h = X @ W via bf16 MFMA. Writes hTf in MFMA-B-fragment order:
// hTf[((chunk*16 + t)*64 + lane)*8 + e] = bf16(h[chunk*32 + (lane>>4)*8 + e][16t + (lane&15)])
__global__ __launch_bounds__(256) void k1_hgemm(const float* __restrict__ input,
                                                const unsigned short* __restrict__ Wt,
                                                const float* __restrict__ a_vec,
                                                unsigned short* __restrict__ hTf,
                                                float* __restrict__ s1_raw,
                                                float* __restrict__ s2_raw) {
    int tid = threadIdx.x;
    int lane = tid & 63;
    int c = lane & 15, g = lane >> 4;
    int r0 = blockIdx.x * 64 + (tid >> 6) * 16;
    f32x4 acc[16];
#pragma unroll
    for (int t = 0; t < 16; ++t) acc[t] = (f32x4){0.f, 0.f, 0.f, 0.f};
    const float* arow = input + (size_t)(r0 + c) * IN_FEAT;
#pragma unroll 1
    for (int kk = 0; kk < IN_FEAT / 32; ++kk) {
        int kb = kk * 32 + 8 * g;
        float4 x0 = *(const float4*)(arow + kb);
        float4 x1 = *(const float4*)(arow + kb + 4);
        u16x8v au;
        au[0] = f2bf(x0.x); au[1] = f2bf(x0.y); au[2] = f2bf(x0.z); au[3] = f2bf(x0.w);
        au[4] = f2bf(x1.x); au[5] = f2bf(x1.y); au[6] = f2bf(x1.z); au[7] = f2bf(x1.w);
        b16x8 af = __builtin_bit_cast(b16x8, au);
#pragma unroll
        for (int t = 0; t < 16; ++t) {
            b16x8 bf = __builtin_bit_cast(b16x8,
                *(const u16x8v*)(Wt + (size_t)(16 * t + c) * IN_FEAT + kb));
            acc[t] = __builtin_amdgcn_mfma_f32_16x16x32_bf16(af, bf, acc[t], 0, 0, 0);
        }
    }
    float a1v[16], a2v[16];
#pragma unroll
    for (int t = 0; t < 16; ++t) {
        a1v[t] = a_vec[16 * t + c];
        a2v[t] = a_vec[OUT_FEAT + 16 * t + c];
    }
#pragma unroll
    for (int r = 0; r < 4; ++r) {
        float s1p = 0.f, s2p = 0.f;
#pragma unroll
        for (int t = 0; t < 16; ++t) { s1p += acc[t][r] * a1v[t]; s2p += acc[t][r] * a2v[t]; }
#pragma unroll
        for (int m = 1; m <= 8; m <<= 1) { s1p += __shfl_xor(s1p, m); s2p += __shfl_xor(s2p, m); }
        if (c == 0) {
            int row = r0 + 4 * g + r;
            s1_raw[row] = s1p;
            s2_raw[row] = s2p;
        }
    }
    int chunk = r0 >> 5;
    int lp = ((r0 & 16) >> 3) + (g >> 1);
    int e0 = 4 * (g & 1);
#pragma unroll
    for (int t = 0; t < 16; ++t) {
        ushort4 pk;
        pk.x = f2bf(acc[t][0]); pk.y = f2bf(acc[t][1]);
        pk.z = f2bf(acc[t][2]); pk.w = f2bf(acc[t][3]);
        *(ushort4*)(hTf + ((size_t)(chunk * 16 + t) * 64 + lp * 16 + c) * 8 + e0) = pk;
    }
}

// K2: M2 = max(s2); per-row constants a_row=(s1-m)*K, m8=-0.8*m*K; s2k=s2*K
__global__ __launch_bounds__(256) void k2_prep(const float* __restrict__ s1_raw,
                                               const float* __restrict__ s2_raw,
                                               float* __restrict__ s2k,
                                               float2* __restrict__ row2) {
    __shared__ float red[256];
    int tid = threadIdx.x;
    float m = -3.0e38f;
    for (int j = tid; j < N_NODES; j += 256) m = fmaxf(m, s2_raw[j]);
    red[tid] = m;
    __syncthreads();
    for (int s = 128; s > 0; s >>= 1) {
        if (tid < s) red[tid] = fmaxf(red[tid], red[tid + s]);
        __syncthreads();
    }
    float M2 = red[0];
    int i = blockIdx.x * 256 + tid;
    float s1 = s1_raw[i];
    float u = s1 + M2;
    float mi = fmaxf(u, 0.2f * u);
    row2[i] = make_float2((s1 - mi) * LOG2E, -0.8f * mi * LOG2E);
    s2k[i] = s2_raw[i] * LOG2E;
}

// K3 v4: LDS-staged flash-GAT partials (2-phase double-buffered, T3 template).
// Grid 512 = 128 rowgroups (64 rows) x 4 jq. 8 waves: (rq 0..3) x (ch 0..1).
// Per chunk: block stages 16KB hTf tile via global_load_lds w16 (linear LDS =
// fragment layout); waves MFMA from ds_read_b128. One barrier/chunk; stage for
// kk+1 issued after the barrier so its latency hides under compute kk.
__global__ __launch_bounds__(512, 4) void k3_flash(const uint32_t* __restrict__ bitsT,
                                                   const unsigned short* __restrict__ hTf,
                                                   const float* __restrict__ s2k,
                                                   const float2* __restrict__ row2,
                                                   float* __restrict__ pout,
                                                   float* __restrict__ rowpart) {
    __shared__ unsigned short tiles[2][8192];   // 2 x 16 KB chunk tiles

    int tid = threadIdx.x;
    int w = tid >> 6, lane = tid & 63;
    int c = lane & 15, g = lane >> 4;
    int ch = w & 1, rq = w >> 1;
    int jq = blockIdx.x & 3;
    int rg = blockIdx.x >> 2;
    int row16 = rg * 64 + rq * 16;

    float2 rc = row2[row16 + c];
    float a_row = rc.x, m8 = rc.y;
    const uint32_t* mrow = bitsT + row16 + c;

    f32x4 acc[8];
#pragma unroll
    for (int t = 0; t < 8; ++t) acc[t] = (f32x4){0.f, 0.f, 0.f, 0.f};
    float lacc = 0.f;

    // wave w stages tiles 2w and 2w+1 of the chunk (1 KB each, lane-linear)
    const size_t chunk_shorts = 16 * 64 * 8;    // 8192 shorts / chunk
    int t0 = 2 * w, t1 = 2 * w + 1;

    {   // prologue: stage chunk kk=0 into tiles[0]
        int jchunk = jq * 64;
        const unsigned short* src0 = hTf + (size_t)jchunk * chunk_shorts + (size_t)(t0 * 64 + lane) * 8;
        const unsigned short* src1 = hTf + (size_t)jchunk * chunk_shorts + (size_t)(t1 * 64 + lane) * 8;
        __builtin_amdgcn_global_load_lds(
            (const __attribute__((address_space(1))) uint32_t*)src0,
            (__attribute__((address_space(3))) uint32_t*)(&tiles[0][t0 * 512]), 16, 0, 0);
        __builtin_amdgcn_global_load_lds(
            (const __attribute__((address_space(1))) uint32_t*)src1,
            (__attribute__((address_space(3))) uint32_t*)(&tiles[0][t1 * 512]), 16, 0, 0);
    }

#pragma unroll 2
    for (int kk = 0; kk < 64; ++kk) {
        int cur = kk & 1;
        __syncthreads();   // drains this wave's global_load_lds (vmcnt0) + all reads of buf cur^1
        if (kk < 63) {     // stage next chunk into the other buffer; latency hides under compute
            int jn = jq * 64 + kk + 1;
            const unsigned short* src0 = hTf + (size_t)jn * chunk_shorts + (size_t)(t0 * 64 + lane) * 8;
            const unsigned short* src1 = hTf + (size_t)jn * chunk_shorts + (size_t)(t1 * 64 + lane) * 8;
            __builtin_amdgcn_global_load_lds(
                (const __attribute__((address_space(1))) uint32_t*)src0,
                (__attribute__((address_space(3))) uint32_t*)(&tiles[cur ^ 1][t0 * 512]), 16, 0, 0);
            __builtin_amdgcn_global_load_lds(
                (const __attribute__((address_space(1))) uint32_t*)src1,
                (__attribute__((address_space(3))) uint32_t*)(&tiles[cur ^ 1][t1 * 512]), 16, 0, 0);
        }

        int jchunk = jq * 64 + kk;
        uint32_t md = mrow[(size_t)jchunk * N_NODES];   // one 64B line, g-broadcast
        uint32_t mb = (md >> (8 * g)) & 0xFFu;
        int jb = jchunk * 32 + 8 * g;
        float4 s0 = *(const float4*)(s2k + jb);
        float4 s1v = *(const float4*)(s2k + jb + 4);
        float sv[8] = {s0.x, s0.y, s0.z, s0.w, s1v.x, s1v.y, s1v.z, s1v.w};
        b16x8 af;
#pragma unroll
        for (int e = 0; e < 8; ++e) {
            float v1 = a_row + sv[e];                  // (e-m)*log2e, pos branch
            float v2 = __builtin_fmaf(v1, 0.2f, m8);   // neg branch
            float arg = fmaxf(v1, v2);                 // <= 0 always
            float pe = __builtin_amdgcn_exp2f(arg);
            float p = (mb & (1u << e)) ? pe : 0.f;
            lacc += p;
            af[e] = (__bf16)p;
        }
        const unsigned short* tb = &tiles[cur][ch * 8 * 512];
#pragma unroll
        for (int t = 0; t < 8; ++t) {
            b16x8 bf = __builtin_bit_cast(b16x8, *(const u16x8v*)(tb + t * 512 + lane * 8));
            acc[t] = __builtin_amdgcn_mfma_f32_16x16x32_bf16(af, bf, acc[t], 0, 0, 0);
        }
    }

    // partial row sums over this j-quarter
    float l1 = lacc + __shfl_xor(lacc, 16);
    float ltot = l1 + __shfl_xor(l1, 32);
    if (ch == 0 && g == 0) rowpart[jq * N_NODES + row16 + c] = ltot;

#pragma unroll
    for (int r = 0; r < 4; ++r) {
        int grow = row16 + 4 * g + r;                  // C layout: row=(lane>>4)*4+r
#pragma unroll
        for (int t = 0; t < 8; ++t) {
            pout[((size_t)jq * N_NODES + grow) * OUT_FEAT + ch * 128 + 16 * t + c] = acc[t][r];
        }
    }
}

// K4: out = elu( (sum_q pout[q]) / (sum_q rowpart[q]) ).
__global__ __launch_bounds__(256) void k4_reduce(const float* __restrict__ pout,
                                                 const float* __restrict__ rowpart,
                                                 float* __restrict__ out) {
    int t = blockIdx.x * 256 + threadIdx.x;
    int row = t >> 8;
    float s = 0.f, l = 0.f;
#pragma unroll
    for (int q = 0; q < 4; ++q) {
        s += pout[(size_t)q * N_NODES * OUT_FEAT + t];
        l += rowpart[q * N_NODES + row];
    }
    float inv = (l > 0.f) ? 1.0f / l : 0.f;
    float x = s * inv;
    out[t] = (x > 0.f) ? x : (__builtin_amdgcn_exp2f(x * LOG2E) - 1.0f);
}

extern "C" void kernel_launch(void* const* d_in, const int* in_sizes, int n_in,
                              void* d_out, int out_size, void* d_ws, size_t ws_size,
                              hipStream_t stream) {
    const float* input = (const float*)d_in[0];
    const int* adj = (const int*)d_in[1];
    const float* W = (const float*)d_in[2];
    const float* a_vec = (const float*)d_in[3];
    float* out = (float*)d_out;

    char* ws = (char*)d_ws;
    unsigned short* Wt  = (unsigned short*)(ws);                 // 256 KB
    unsigned short* hTf = (unsigned short*)(ws + 262144);        // 4 MB
    float*  s2k     = (float*)(ws + 4456448);                    // 32 KB
    float2* row2    = (float2*)(ws + 4489216);                   // 64 KB
    float*  s1_raw  = (float*)(ws + 4554752);                    // 32 KB
    float*  s2_raw  = (float*)(ws + 4587520);                    // 32 KB
    uint32_t* bitsT = (uint32_t*)(ws + 4620288);                 // 8 MB
    float*  rowpart = (float*)(ws + 13008896);                   // 128 KB
    float*  pout    = (float*)(ws + 13139968);                   // 32 MB

    hipLaunchKernelGGL(k_pack, dim3(128, 64), dim3(256), 0, stream, adj, bitsT);
    hipLaunchKernelGGL(k0_transpose_w, dim3(512), dim3(256), 0, stream, W, Wt);
    hipLaunchKernelGGL(k1_hgemm, dim3(N_NODES / 64), dim3(256), 0, stream,
                       input, Wt, a_vec, hTf, s1_raw, s2_raw);
    hipLaunchKernelGGL(k2_prep, dim3(32), dim3(256), 0, stream, s1_raw, s2_raw, s2k, row2);
    hipLaunchKernelGGL(k3_flash, dim3(512), dim3(512), 0, stream,
                       bitsT, hTf, s2k, row2, pout, rowpart);
    hipLaunchKernelGGL(k4_reduce, dim3(N_NODES * OUT_FEAT / 256), dim3(256), 0, stream,
                       pout, rowpart, out);
}

// Round 6
// 170.094 us; speedup vs baseline: 3.1146x; 1.2173x over previous
//
#include <hip/hip_runtime.h>
#include <stdint.h>

#define N_NODES 8192
#define IN_FEAT 512
#define OUT_FEAT 256
#define LOG2E 1.4426950408889634f

typedef __bf16 b16x8 __attribute__((ext_vector_type(8)));
typedef unsigned short u16x8v __attribute__((ext_vector_type(8)));
typedef float f32x4 __attribute__((ext_vector_type(4)));

static __device__ __forceinline__ unsigned short f2bf(float f) {
    union { float f; uint32_t u; } v; v.f = f;
    uint32_t r = v.u + 0x7FFFu + ((v.u >> 16) & 1u);
    return (unsigned short)(r >> 16);
}

// K_pack: adj int32 [8192][8192] -> ROW-MAJOR bitmask bitsR (8 MB).
// byte t = bits for cols [8*(t%1024), +8) of row t/1024. Fully coalesced reads
// (lane-interleaved int4: per-instr 32 lines, all bytes used).
__global__ __launch_bounds__(256) void k_pack(const int* __restrict__ adj,
                                              unsigned char* __restrict__ bitsR) {
    size_t t = (size_t)blockIdx.x * 256 + threadIdx.x;
    const int4* a4 = (const int4*)adj + t * 2;
    int4 x0 = a4[0];
    int4 x1 = a4[1];
    unsigned b = (unsigned)(x0.x != 0)
               | ((unsigned)(x0.y != 0) << 1)
               | ((unsigned)(x0.z != 0) << 2)
               | ((unsigned)(x0.w != 0) << 3)
               | ((unsigned)(x1.x != 0) << 4)
               | ((unsigned)(x1.y != 0) << 5)
               | ((unsigned)(x1.z != 0) << 6)
               | ((unsigned)(x1.w != 0) << 7);
    bitsR[t] = (unsigned char)b;
}

// K0: Wt[c][k] = bf16(W[k][c])  (256 x 512)
__global__ __launch_bounds__(256) void k0_transpose_w(const float* __restrict__ W,
                                                      unsigned short* __restrict__ Wt) {
    int tid = blockIdx.x * 256 + threadIdx.x;
    int c = tid & (OUT_FEAT - 1);
    int k = tid >> 8;
    Wt[(size_t)c * IN_FEAT + k] = f2bf(W[(size_t)k * OUT_FEAT + c]);
}

// K1: h = X @ W via bf16 MFMA. Writes hTf in MFMA-B-fragment order:
// hTf[((chunk*16 + t)*64 + lane)*8 + e] = bf16(h[chunk*32 + (lane>>4)*8 + e][16t + (lane&15)])
__global__ __launch_bounds__(256) void k1_hgemm(const float* __restrict__ input,
                                                const unsigned short* __restrict__ Wt,
                                                const float* __restrict__ a_vec,
                                                unsigned short* __restrict__ hTf,
                                                float* __restrict__ s1_raw,
                                                float* __restrict__ s2_raw) {
    int tid = threadIdx.x;
    int lane = tid & 63;
    int c = lane & 15, g = lane >> 4;
    int r0 = blockIdx.x * 64 + (tid >> 6) * 16;
    f32x4 acc[16];
#pragma unroll
    for (int t = 0; t < 16; ++t) acc[t] = (f32x4){0.f, 0.f, 0.f, 0.f};
    const float* arow = input + (size_t)(r0 + c) * IN_FEAT;
#pragma unroll 1
    for (int kk = 0; kk < IN_FEAT / 32; ++kk) {
        int kb = kk * 32 + 8 * g;
        float4 x0 = *(const float4*)(arow + kb);
        float4 x1 = *(const float4*)(arow + kb + 4);
        u16x8v au;
        au[0] = f2bf(x0.x); au[1] = f2bf(x0.y); au[2] = f2bf(x0.z); au[3] = f2bf(x0.w);
        au[4] = f2bf(x1.x); au[5] = f2bf(x1.y); au[6] = f2bf(x1.z); au[7] = f2bf(x1.w);
        b16x8 af = __builtin_bit_cast(b16x8, au);
#pragma unroll
        for (int t = 0; t < 16; ++t) {
            b16x8 bf = __builtin_bit_cast(b16x8,
                *(const u16x8v*)(Wt + (size_t)(16 * t + c) * IN_FEAT + kb));
            acc[t] = __builtin_amdgcn_mfma_f32_16x16x32_bf16(af, bf, acc[t], 0, 0, 0);
        }
    }
    float a1v[16], a2v[16];
#pragma unroll
    for (int t = 0; t < 16; ++t) {
        a1v[t] = a_vec[16 * t + c];
        a2v[t] = a_vec[OUT_FEAT + 16 * t + c];
    }
#pragma unroll
    for (int r = 0; r < 4; ++r) {
        float s1p = 0.f, s2p = 0.f;
#pragma unroll
        for (int t = 0; t < 16; ++t) { s1p += acc[t][r] * a1v[t]; s2p += acc[t][r] * a2v[t]; }
#pragma unroll
        for (int m = 1; m <= 8; m <<= 1) { s1p += __shfl_xor(s1p, m); s2p += __shfl_xor(s2p, m); }
        if (c == 0) {
            int row = r0 + 4 * g + r;
            s1_raw[row] = s1p;
            s2_raw[row] = s2p;
        }
    }
    int chunk = r0 >> 5;
    int lp = ((r0 & 16) >> 3) + (g >> 1);
    int e0 = 4 * (g & 1);
#pragma unroll
    for (int t = 0; t < 16; ++t) {
        ushort4 pk;
        pk.x = f2bf(acc[t][0]); pk.y = f2bf(acc[t][1]);
        pk.z = f2bf(acc[t][2]); pk.w = f2bf(acc[t][3]);
        *(ushort4*)(hTf + ((size_t)(chunk * 16 + t) * 64 + lp * 16 + c) * 8 + e0) = pk;
    }
}

// K2: M2 = max(s2); per-row constants a_row=(s1-m)*K, m8=-0.8*m*K; s2k=s2*K
__global__ __launch_bounds__(256) void k2_prep(const float* __restrict__ s1_raw,
                                               const float* __restrict__ s2_raw,
                                               float* __restrict__ s2k,
                                               float2* __restrict__ row2) {
    __shared__ float red[256];
    int tid = threadIdx.x;
    float m = -3.0e38f;
    for (int j = tid; j < N_NODES; j += 256) m = fmaxf(m, s2_raw[j]);
    red[tid] = m;
    __syncthreads();
    for (int s = 128; s > 0; s >>= 1) {
        if (tid < s) red[tid] = fmaxf(red[tid], red[tid + s]);
        __syncthreads();
    }
    float M2 = red[0];
    int i = blockIdx.x * 256 + tid;
    float s1 = s1_raw[i];
    float u = s1 + M2;
    float mi = fmaxf(u, 0.2f * u);
    row2[i] = make_float2((s1 - mi) * LOG2E, -0.8f * mi * LOG2E);
    s2k[i] = s2_raw[i] * LOG2E;
}

// K3 v5: flash-GAT partials, fully LDS-fed inner loop.
// Grid 512 = 128 rowgroups (64 rows) x 4 jq. 8 waves: (rq 0..3) x (ch 0..1).
// Prologue stages: 64x64 mask dwords (pad 68 -> (4c+kk)%32 banks, 2-way=free)
// + s2k quarter (8 KB). Loop: hTf via double-buffered global_load_lds tiles;
// masks+s2k from LDS; only in-loop global ops are the 2 stage issues.
__global__ __launch_bounds__(512, 4) void k3_flash(const uint32_t* __restrict__ bitsR,
                                                   const unsigned short* __restrict__ hTf,
                                                   const float* __restrict__ s2k,
                                                   const float2* __restrict__ row2,
                                                   float* __restrict__ pout,
                                                   float* __restrict__ rowpart) {
    __shared__ unsigned short tiles[2][8192];   // 32 KB hTf chunk tiles
    __shared__ uint32_t lmask[64 * 68];         // 17 KB mask slab, row pitch 68
    __shared__ float ls2k[2048];                // 8 KB s2k quarter

    int tid = threadIdx.x;
    int w = tid >> 6, lane = tid & 63;
    int c = lane & 15, g = lane >> 4;
    int ch = w & 1, rq = w >> 1;
    int jq = blockIdx.x & 3;
    int rg = blockIdx.x >> 2;
    int row16 = rg * 64 + rq * 16;

    // ---- prologue staging (coalesced) ----
    // masks: rows rg*64..+64, dwords jq*64..+64 (256 B/row, 16 threads/row, 2 passes)
#pragma unroll
    for (int p = 0; p < 2; ++p) {
        int ri = p * 32 + (tid >> 4);
        int dq = (tid & 15) * 4;
        uint4 v = *(const uint4*)(bitsR + (size_t)(rg * 64 + ri) * 256 + jq * 64 + dq);
        *(uint4*)&lmask[ri * 68 + dq] = v;
    }
    // s2k quarter: 2048 floats
    *(float4*)&ls2k[tid * 4] = *(const float4*)(s2k + jq * 2048 + tid * 4);

    float2 rc = row2[row16 + c];
    float a_row = rc.x, m8 = rc.y;

    f32x4 acc[8];
#pragma unroll
    for (int t = 0; t < 8; ++t) acc[t] = (f32x4){0.f, 0.f, 0.f, 0.f};
    float lacc = 0.f;

    const size_t chunk_shorts = 16 * 64 * 8;    // 8192 shorts / chunk
    int t0 = 2 * w, t1 = 2 * w + 1;

    {   // stage chunk kk=0 into tiles[0]
        int jchunk = jq * 64;
        const unsigned short* src0 = hTf + (size_t)jchunk * chunk_shorts + (size_t)(t0 * 64 + lane) * 8;
        const unsigned short* src1 = hTf + (size_t)jchunk * chunk_shorts + (size_t)(t1 * 64 + lane) * 8;
        __builtin_amdgcn_global_load_lds(
            (const __attribute__((address_space(1))) uint32_t*)src0,
            (__attribute__((address_space(3))) uint32_t*)(&tiles[0][t0 * 512]), 16, 0, 0);
        __builtin_amdgcn_global_load_lds(
            (const __attribute__((address_space(1))) uint32_t*)src1,
            (__attribute__((address_space(3))) uint32_t*)(&tiles[0][t1 * 512]), 16, 0, 0);
    }

    const uint32_t* mrow = &lmask[(rq * 16 + c) * 68];

#pragma unroll 2
    for (int kk = 0; kk < 64; ++kk) {
        int cur = kk & 1;
        __syncthreads();   // drains stage loads for this buffer + prior reads of other buffer
        if (kk < 63) {     // stage next chunk; latency hides under compute kk
            int jn = jq * 64 + kk + 1;
            const unsigned short* src0 = hTf + (size_t)jn * chunk_shorts + (size_t)(t0 * 64 + lane) * 8;
            const unsigned short* src1 = hTf + (size_t)jn * chunk_shorts + (size_t)(t1 * 64 + lane) * 8;
            __builtin_amdgcn_global_load_lds(
                (const __attribute__((address_space(1))) uint32_t*)src0,
                (__attribute__((address_space(3))) uint32_t*)(&tiles[cur ^ 1][t0 * 512]), 16, 0, 0);
            __builtin_amdgcn_global_load_lds(
                (const __attribute__((address_space(1))) uint32_t*)src1,
                (__attribute__((address_space(3))) uint32_t*)(&tiles[cur ^ 1][t1 * 512]), 16, 0, 0);
        }

        uint32_t md = mrow[kk];                        // ds_read_b32, 2-way alias = free
        uint32_t mb = (md >> (8 * g)) & 0xFFu;
        const float* sp = &ls2k[kk * 32 + 8 * g];
        float4 s0 = *(const float4*)sp;
        float4 s1v = *(const float4*)(sp + 4);
        float sv[8] = {s0.x, s0.y, s0.z, s0.w, s1v.x, s1v.y, s1v.z, s1v.w};
        b16x8 af;
#pragma unroll
        for (int e = 0; e < 8; ++e) {
            float v1 = a_row + sv[e];                  // (e-m)*log2e, pos branch
            float v2 = __builtin_fmaf(v1, 0.2f, m8);   // neg branch
            float arg = fmaxf(v1, v2);                 // <= 0 always
            float pe = __builtin_amdgcn_exp2f(arg);
            float p = (mb & (1u << e)) ? pe : 0.f;
            lacc += p;
            af[e] = (__bf16)p;
        }
        const unsigned short* tb = &tiles[cur][ch * 8 * 512];
#pragma unroll
        for (int t = 0; t < 8; ++t) {
            b16x8 bf = __builtin_bit_cast(b16x8, *(const u16x8v*)(tb + t * 512 + lane * 8));
            acc[t] = __builtin_amdgcn_mfma_f32_16x16x32_bf16(af, bf, acc[t], 0, 0, 0);
        }
    }

    // partial row sums over this j-quarter
    float l1 = lacc + __shfl_xor(lacc, 16);
    float ltot = l1 + __shfl_xor(l1, 32);
    if (ch == 0 && g == 0) rowpart[jq * N_NODES + row16 + c] = ltot;

#pragma unroll
    for (int r = 0; r < 4; ++r) {
        int grow = row16 + 4 * g + r;                  // C layout: row=(lane>>4)*4+r
#pragma unroll
        for (int t = 0; t < 8; ++t) {
            pout[((size_t)jq * N_NODES + grow) * OUT_FEAT + ch * 128 + 16 * t + c] = acc[t][r];
        }
    }
}

// K4: out = elu( (sum_q pout[q]) / (sum_q rowpart[q]) ).
__global__ __launch_bounds__(256) void k4_reduce(const float* __restrict__ pout,
                                                 const float* __restrict__ rowpart,
                                                 float* __restrict__ out) {
    int t = blockIdx.x * 256 + threadIdx.x;
    int row = t >> 8;
    float s = 0.f, l = 0.f;
#pragma unroll
    for (int q = 0; q < 4; ++q) {
        s += pout[(size_t)q * N_NODES * OUT_FEAT + t];
        l += rowpart[q * N_NODES + row];
    }
    float inv = (l > 0.f) ? 1.0f / l : 0.f;
    float x = s * inv;
    out[t] = (x > 0.f) ? x : (__builtin_amdgcn_exp2f(x * LOG2E) - 1.0f);
}

extern "C" void kernel_launch(void* const* d_in, const int* in_sizes, int n_in,
                              void* d_out, int out_size, void* d_ws, size_t ws_size,
                              hipStream_t stream) {
    const float* input = (const float*)d_in[0];
    const int* adj = (const int*)d_in[1];
    const float* W = (const float*)d_in[2];
    const float* a_vec = (const float*)d_in[3];
    float* out = (float*)d_out;

    char* ws = (char*)d_ws;
    unsigned short* Wt  = (unsigned short*)(ws);                 // 256 KB
    unsigned short* hTf = (unsigned short*)(ws + 262144);        // 4 MB
    float*  s2k     = (float*)(ws + 4456448);                    // 32 KB
    float2* row2    = (float2*)(ws + 4489216);                   // 64 KB
    float*  s1_raw  = (float*)(ws + 4554752);                    // 32 KB
    float*  s2_raw  = (float*)(ws + 4587520);                    // 32 KB
    unsigned char* bitsR = (unsigned char*)(ws + 4620288);       // 8 MB
    float*  rowpart = (float*)(ws + 13008896);                   // 128 KB
    float*  pout    = (float*)(ws + 13139968);                   // 32 MB

    hipLaunchKernelGGL(k_pack, dim3(32768), dim3(256), 0, stream, adj, bitsR);
    hipLaunchKernelGGL(k0_transpose_w, dim3(512), dim3(256), 0, stream, W, Wt);
    hipLaunchKernelGGL(k1_hgemm, dim3(N_NODES / 64), dim3(256), 0, stream,
                       input, Wt, a_vec, hTf, s1_raw, s2_raw);
    hipLaunchKernelGGL(k2_prep, dim3(32), dim3(256), 0, stream, s1_raw, s2_raw, s2k, row2);
    hipLaunchKernelGGL(k3_flash, dim3(512), dim3(512), 0, stream,
                       (const uint32_t*)bitsR, hTf, s2k, row2, pout, rowpart);
    hipLaunchKernelGGL(k4_reduce, dim3(N_NODES * OUT_FEAT / 256), dim3(256), 0, stream,
                       pout, rowpart, out);
}